// Round 1
// baseline (1464.390 us; speedup 1.0000x reference)
//
#include <hip/hip_runtime.h>
#include <math.h>

#define B_   4
#define C_   256
#define C8_  32
#define N_   4096   // H*W = 64*64

// ---------------------------------------------------------------------------
// Projection: Y[b][o][n] = sum_c W[o][c] * X[b][c][n] + bias[o]
// Block tile: 128 n x 32 o, 256 threads, thread = 2n x 8o
// grid = (N/128, O/32, B)
// ---------------------------------------------------------------------------
__global__ __launch_bounds__(256) void proj_kernel(
    const float* __restrict__ X, const float* __restrict__ Wt,
    const float* __restrict__ bias, float* __restrict__ Y, int O)
{
    __shared__ __align__(16) float Ws[32][68];   // 68: b128-aligned, broadcast reads
    const int t  = threadIdx.x;
    const int n0 = blockIdx.x * 128;
    const int o0 = blockIdx.y * 32;
    const int b  = blockIdx.z;
    const int nd = t & 63;          // rows n0+nd, n0+64+nd
    const int og = t >> 6;          // o = o0 + og*8 + j

    float acc0[8], acc1[8];
#pragma unroll
    for (int j = 0; j < 8; ++j) { acc0[j] = 0.f; acc1[j] = 0.f; }

    const float* Xb = X + (size_t)b * C_ * N_;

    for (int c0 = 0; c0 < C_; c0 += 64) {
        // stage W chunk [32 o][64 c]
#pragma unroll
        for (int i = 0; i < 8; ++i) {
            int idx = t + i * 256;             // 0..2047
            int oo = idx >> 6, cc = idx & 63;
            Ws[oo][cc] = Wt[(size_t)(o0 + oo) * C_ + c0 + cc];
        }
        __syncthreads();
#pragma unroll
        for (int c4 = 0; c4 < 16; ++c4) {
            float x0[4], x1[4];
#pragma unroll
            for (int e = 0; e < 4; ++e) {
                int c = c0 + c4 * 4 + e;
                x0[e] = Xb[(size_t)c * N_ + n0 + nd];
                x1[e] = Xb[(size_t)c * N_ + n0 + 64 + nd];
            }
#pragma unroll
            for (int j = 0; j < 8; ++j) {
                const float4 w = *(const float4*)&Ws[og * 8 + j][c4 * 4];
                acc0[j] = fmaf(w.x, x0[0], acc0[j]);
                acc0[j] = fmaf(w.y, x0[1], acc0[j]);
                acc0[j] = fmaf(w.z, x0[2], acc0[j]);
                acc0[j] = fmaf(w.w, x0[3], acc0[j]);
                acc1[j] = fmaf(w.x, x1[0], acc1[j]);
                acc1[j] = fmaf(w.y, x1[1], acc1[j]);
                acc1[j] = fmaf(w.z, x1[2], acc1[j]);
                acc1[j] = fmaf(w.w, x1[3], acc1[j]);
            }
        }
        __syncthreads();
    }
#pragma unroll
    for (int j = 0; j < 8; ++j) {
        int o = o0 + og * 8 + j;
        float bi = bias[o];
        Y[((size_t)b * O + o) * N_ + n0 + nd]      = acc0[j] + bi;
        Y[((size_t)b * O + o) * N_ + n0 + 64 + nd] = acc1[j] + bi;
    }
}

// ---------------------------------------------------------------------------
// Fused flash attention (f32).
// Q,K: [B][32][N]  V: [B][256][N]  TOP: [B][256][N]  OUT: [B][256][N]
// Block: 512 threads, 64 query rows, iterate 64-key tiles over all 4096 keys.
//   S-role:  n_s = t>>3 (row), mg = t&7, m = mg + 8i  (row-reduce = shfl in 8-lane group)
//   PV-role: rg = t>>4 (rows 2rg,2rg+1), cg = t&15 (cols 4cg + 64q + e)
// grid = (N/64, B)
// ---------------------------------------------------------------------------
#define RTILE 64
#define MTILE 64
#define VSTR  260    // 260%32=4 -> b128 reads 2-way max; 1040B rows, 16B aligned
#define KSTR  36     // 144B rows, 16B aligned; reads are wave-broadcast
#define PSTR  66     // float2 reads 8B aligned; writes (2m+n)%32 conflict-free
#define ESTR  257    // epilogue transpose: reads (n+c)%32 conflict-free

__global__ __launch_bounds__(512) void attn_kernel(
    const float* __restrict__ Q, const float* __restrict__ K,
    const float* __restrict__ V, const float* __restrict__ TOP,
    float* __restrict__ OUT)
{
    __shared__ __align__(16) float vs[MTILE * VSTR];   // 66.6 KB (reused for epilogue)
    __shared__ __align__(16) float ks[MTILE * KSTR];   // 9.2 KB
    __shared__ __align__(16) float qs[RTILE * KSTR];   // 9.2 KB
    __shared__ __align__(16) float Ps[MTILE * PSTR];   // 16.9 KB
    __shared__ float fsc[64];
    __shared__ float lrow[64];

    const int t  = threadIdx.x;
    const int b  = blockIdx.y;
    const int n0 = blockIdx.x * RTILE;

    // S-role ids
    const int n_s = t >> 3;
    const int mg  = t & 7;
    // PV-role ids
    const int rg  = t >> 4;   // 0..31
    const int cg  = t & 15;   // 0..15

    // stage q tile [64 n][32 c]
#pragma unroll
    for (int it = 0; it < 4; ++it) {
        int flat = it * 512 + t;            // 0..2047
        int o = flat >> 6, nn = flat & 63;
        qs[nn * KSTR + o] = Q[((size_t)b * C8_ + o) * N_ + n0 + nn];
    }
    __syncthreads();

    float4 qreg[8];
#pragma unroll
    for (int c4 = 0; c4 < 8; ++c4)
        qreg[c4] = *(const float4*)&qs[n_s * KSTR + c4 * 4];

    float m_run = -1e30f, l_run = 0.f;
    float acc0[16], acc1[16];
#pragma unroll
    for (int j = 0; j < 16; ++j) { acc0[j] = 0.f; acc1[j] = 0.f; }

    for (int kt = 0; kt < N_ / MTILE; ++kt) {
        const int m0 = kt * MTILE;
        __syncthreads();   // previous tile's vs/ks/Ps fully consumed
        // stage k tile [64 m][32 c]
#pragma unroll
        for (int it = 0; it < 4; ++it) {
            int flat = it * 512 + t;
            int o = flat >> 6, mm = flat & 63;
            ks[mm * KSTR + o] = K[((size_t)b * C8_ + o) * N_ + m0 + mm];
        }
        // stage v tile [64 m][256 c] (transposed from [c][m] global)
#pragma unroll
        for (int it = 0; it < 32; ++it) {
            int flat = it * 512 + t;        // 0..16383
            int o = flat >> 6, mm = flat & 63;
            vs[mm * VSTR + o] = V[((size_t)b * C_ + o) * N_ + m0 + mm];
        }
        __syncthreads();

        // ---- S phase: s_[i] = q[n_s] . k[mg + 8i] ----
        float s_[8];
#pragma unroll
        for (int i = 0; i < 8; ++i) {
            int m = mg + i * 8;
            float a = 0.f;
#pragma unroll
            for (int c4 = 0; c4 < 8; ++c4) {
                const float4 kk = *(const float4*)&ks[m * KSTR + c4 * 4];
                a = fmaf(kk.x, qreg[c4].x, a);
                a = fmaf(kk.y, qreg[c4].y, a);
                a = fmaf(kk.z, qreg[c4].z, a);
                a = fmaf(kk.w, qreg[c4].w, a);
            }
            s_[i] = a;
        }
        // ---- online softmax (row = 8-lane shuffle group) ----
        float tm = s_[0];
#pragma unroll
        for (int i = 1; i < 8; ++i) tm = fmaxf(tm, s_[i]);
#pragma unroll
        for (int d = 1; d < 8; d <<= 1) tm = fmaxf(tm, __shfl_xor(tm, d));
        float mo = m_run;
        float mn = fmaxf(mo, tm);
        float f  = __expf(mo - mn);
        m_run = mn;
        float psum = 0.f;
#pragma unroll
        for (int i = 0; i < 8; ++i) {
            float p = __expf(s_[i] - mn);
            psum += p;
            Ps[(mg + i * 8) * PSTR + n_s] = p;
        }
#pragma unroll
        for (int d = 1; d < 8; d <<= 1) psum += __shfl_xor(psum, d);
        l_run = l_run * f + psum;
        if (mg == 0) fsc[n_s] = f;
        __syncthreads();   // Ps + fsc visible

        // ---- PV phase ----
        float f0 = fsc[rg * 2], f1 = fsc[rg * 2 + 1];
#pragma unroll
        for (int j = 0; j < 16; ++j) { acc0[j] *= f0; acc1[j] *= f1; }
#pragma unroll 4
        for (int m = 0; m < MTILE; ++m) {
            const float2 p2 = *(const float2*)&Ps[m * PSTR + rg * 2];
#pragma unroll
            for (int q = 0; q < 4; ++q) {
                const float4 v4 = *(const float4*)&vs[m * VSTR + cg * 4 + q * 64];
                acc0[q*4+0] = fmaf(p2.x, v4.x, acc0[q*4+0]);
                acc0[q*4+1] = fmaf(p2.x, v4.y, acc0[q*4+1]);
                acc0[q*4+2] = fmaf(p2.x, v4.z, acc0[q*4+2]);
                acc0[q*4+3] = fmaf(p2.x, v4.w, acc0[q*4+3]);
                acc1[q*4+0] = fmaf(p2.y, v4.x, acc1[q*4+0]);
                acc1[q*4+1] = fmaf(p2.y, v4.y, acc1[q*4+1]);
                acc1[q*4+2] = fmaf(p2.y, v4.z, acc1[q*4+2]);
                acc1[q*4+3] = fmaf(p2.y, v4.w, acc1[q*4+3]);
            }
        }
    }

    if (mg == 0) lrow[n_s] = l_run;
    __syncthreads();   // all PV reads of vs done; lrow visible

    // epilogue: transpose via LDS (reuse vs as [64][ESTR]) for coalesced stores
    {
        float li0 = 1.f / lrow[rg * 2];
        float li1 = 1.f / lrow[rg * 2 + 1];
#pragma unroll
        for (int q = 0; q < 4; ++q)
#pragma unroll
            for (int e = 0; e < 4; ++e) {
                int c = cg * 4 + q * 64 + e;
                vs[(rg * 2)     * ESTR + c] = acc0[q * 4 + e] * li0;
                vs[(rg * 2 + 1) * ESTR + c] = acc1[q * 4 + e] * li1;
            }
    }
    __syncthreads();
#pragma unroll
    for (int it = 0; it < 32; ++it) {
        int flat = it * 512 + t;            // 0..16383
        int n = flat & 63, c = flat >> 6;
        size_t g = ((size_t)b * C_ + c) * N_ + n0 + n;
        OUT[g] = TOP[g] + vs[n * ESTR + c];
    }
}

// ---------------------------------------------------------------------------
extern "C" void kernel_launch(void* const* d_in, const int* in_sizes, int n_in,
                              void* d_out, int out_size, void* d_ws, size_t ws_size,
                              hipStream_t stream)
{
    const float* top  = (const float*)d_in[0];
    const float* side = (const float*)d_in[1];
    const float* Wq   = (const float*)d_in[2];
    const float* bq   = (const float*)d_in[3];
    const float* Wk   = (const float*)d_in[4];
    const float* bk   = (const float*)d_in[5];
    const float* Wv   = (const float*)d_in[6];
    const float* bv   = (const float*)d_in[7];
    float* out = (float*)d_out;

    float* Q = (float*)d_ws;                       // [B][32][N]
    float* K = Q + (size_t)B_ * C8_ * N_;          // [B][32][N]
    float* V = K + (size_t)B_ * C8_ * N_;          // [B][256][N]

    proj_kernel<<<dim3(N_ / 128, 1, B_), dim3(256), 0, stream>>>(top,  Wq, bq, Q, C8_);
    proj_kernel<<<dim3(N_ / 128, 1, B_), dim3(256), 0, stream>>>(side, Wk, bk, K, C8_);
    proj_kernel<<<dim3(N_ / 128, 8, B_), dim3(256), 0, stream>>>(side, Wv, bv, V, C_);
    attn_kernel<<<dim3(N_ / RTILE, B_), dim3(512), 0, stream>>>(Q, K, V, top, out);
}

// Round 2
// 476.289 us; speedup vs baseline: 3.0746x; 3.0746x over previous
//
#include <hip/hip_runtime.h>
#include <math.h>

#define B_   4
#define C_   256
#define C8_  32
#define N_   4096   // H*W

typedef float f32x4 __attribute__((ext_vector_type(4)));
typedef short s16x8 __attribute__((ext_vector_type(8)));

static __device__ __forceinline__ short f2bf(float x) {   // RNE f32->bf16 bits
    unsigned u = __builtin_bit_cast(unsigned, x);
    u = (u + 0x7fffu + ((u >> 16) & 1u)) >> 16;
    return (short)u;
}
static __device__ __forceinline__ float bf2f(short s) {
    unsigned u = ((unsigned)(unsigned short)s) << 16;
    return __builtin_bit_cast(float, u);
}

// ---------------------------------------------------------------------------
// Projection: Y[b][o][n] = sum_c W[o][c] * X[b][c][n] + bias[o]
// 128n x 32o tile, 256 threads. BF16OUT=true stores bf16 bits (for V).
// ---------------------------------------------------------------------------
template <bool BF16OUT>
__global__ __launch_bounds__(256) void proj_kernel(
    const float* __restrict__ X, const float* __restrict__ Wt,
    const float* __restrict__ bias, void* __restrict__ Yv, int O)
{
    __shared__ __align__(16) float Ws[32][68];
    const int t  = threadIdx.x;
    const int n0 = blockIdx.x * 128;
    const int o0 = blockIdx.y * 32;
    const int b  = blockIdx.z;
    const int nd = t & 63;
    const int og = t >> 6;

    float acc0[8], acc1[8];
#pragma unroll
    for (int j = 0; j < 8; ++j) { acc0[j] = 0.f; acc1[j] = 0.f; }

    const float* Xb = X + (size_t)b * C_ * N_;

    for (int c0 = 0; c0 < C_; c0 += 64) {
#pragma unroll
        for (int i = 0; i < 8; ++i) {
            int idx = t + i * 256;
            int oo = idx >> 6, cc = idx & 63;
            Ws[oo][cc] = Wt[(size_t)(o0 + oo) * C_ + c0 + cc];
        }
        __syncthreads();
#pragma unroll
        for (int c4 = 0; c4 < 16; ++c4) {
            float x0[4], x1[4];
#pragma unroll
            for (int e = 0; e < 4; ++e) {
                int c = c0 + c4 * 4 + e;
                x0[e] = Xb[(size_t)c * N_ + n0 + nd];
                x1[e] = Xb[(size_t)c * N_ + n0 + 64 + nd];
            }
#pragma unroll
            for (int j = 0; j < 8; ++j) {
                const float4 w = *(const float4*)&Ws[og * 8 + j][c4 * 4];
                acc0[j] = fmaf(w.x, x0[0], acc0[j]);
                acc0[j] = fmaf(w.y, x0[1], acc0[j]);
                acc0[j] = fmaf(w.z, x0[2], acc0[j]);
                acc0[j] = fmaf(w.w, x0[3], acc0[j]);
                acc1[j] = fmaf(w.x, x1[0], acc1[j]);
                acc1[j] = fmaf(w.y, x1[1], acc1[j]);
                acc1[j] = fmaf(w.z, x1[2], acc1[j]);
                acc1[j] = fmaf(w.w, x1[3], acc1[j]);
            }
        }
        __syncthreads();
    }
#pragma unroll
    for (int j = 0; j < 8; ++j) {
        int o = o0 + og * 8 + j;
        float bi = bias[o];
        size_t base = ((size_t)b * O + o) * N_ + n0 + nd;
        float v0 = acc0[j] + bi, v1 = acc1[j] + bi;
        if constexpr (BF16OUT) {
            ((short*)Yv)[base]      = f2bf(v0);
            ((short*)Yv)[base + 64] = f2bf(v1);
        } else {
            ((float*)Yv)[base]      = v0;
            ((float*)Yv)[base + 64] = v1;
        }
    }
}

// ---------------------------------------------------------------------------
// Fused flash attention. QK^T + softmax in exact f32 (VALU), PV via bf16 MFMA.
// Q,K: [B][32][N] f32   V: [B][256][N] bf16   TOP/OUT: [B][256][N] f32
// Block: 512 thr (8 waves), 32 q-rows, 64-key tiles. grid (N/32, B) = 512 blocks.
// S-role:  n_s=t>>4 (row 0..31), mg=t&15, m = mg+16i  (16-lane shfl row-reduce)
// PV-role: wave w: wn=w>>2 (16-row half), wc=w&3 (64-col quarter); MFMA 16x16x32.
//   A-frag P[n][m]: lane: row wn*16+(l&15), m = kk*32+(l>>4)*8+j
//   B-frag V^T[c][m]: lane: row wc*64+cf*16+(l&15), same m
//   D: col(l&15)=c, row(l>>4)*4+r = n          [m89-verified layout]
// LDS XOR swizzle (byte ^= (row&7)<<4) on Ps and vs -> 2-way max conflicts.
// ---------------------------------------------------------------------------
#define RT 32
#define MT 64
#define KSTR 44      // f32 row stride: 176B, 16B-aligned, bank-spread 2-way

#define VS_OFF 0                     // [256][64] bf16 swizzled : 32768 B
#define KS_OFF 32768                 // [64][KSTR] f32          : 11264 B
#define QS_OFF 44032                 // [32][KSTR] f32          :  5632 B
#define PS_OFF 49664                 // [32][64] bf16 swizzled  :  4096 B
#define FS_OFF 53760                 // fsc[32] f32 (+pad)      :   128 B
#define LR_OFF 53888                 // lrow[32] f32 (+pad)     :   128 B
#define SMEM_BYTES 54016

__global__ __launch_bounds__(512, 4) void attn_kernel(
    const float* __restrict__ Q, const float* __restrict__ K,
    const short* __restrict__ V, const float* __restrict__ TOP,
    float* __restrict__ OUT)
{
    __shared__ __align__(16) char smem[SMEM_BYTES];
    float* ksm  = (float*)(smem + KS_OFF);
    float* qsm  = (float*)(smem + QS_OFF);
    float* fsc  = (float*)(smem + FS_OFF);
    float* lrow = (float*)(smem + LR_OFF);

    const int t    = threadIdx.x;
    const int b    = blockIdx.y;
    const int n0   = blockIdx.x * RT;
    const int lane = t & 63;
    const int w    = t >> 6;
    const int n_s  = t >> 4;
    const int mg   = t & 15;
    const int wn   = w >> 2;
    const int wc   = w & 3;
    const int tq   = lane >> 4;
    const int tc   = lane & 15;

    // stage q [32 n][32 c] -> qsm
#pragma unroll
    for (int it = 0; it < 2; ++it) {
        int flat = it * 512 + t;
        int o = flat >> 5, nn = flat & 31;
        qsm[nn * KSTR + o] = Q[((size_t)b * C8_ + o) * N_ + n0 + nn];
    }
    __syncthreads();

    float4 qreg[8];
#pragma unroll
    for (int c4 = 0; c4 < 8; ++c4)
        qreg[c4] = *(const float4*)&qsm[n_s * KSTR + c4 * 4];

    float m_run = -1e30f, l_run = 0.f;
    f32x4 acc[4];
#pragma unroll
    for (int cf = 0; cf < 4; ++cf) acc[cf] = 0.f;

    for (int kt = 0; kt < N_ / MT; ++kt) {
        const int m0 = kt * MT;
        __syncthreads();   // prior tile fully consumed
        // stage K tile [64 m][32 c] f32
#pragma unroll
        for (int it = 0; it < 4; ++it) {
            int flat = it * 512 + t;
            int o = flat >> 6, mm = flat & 63;
            ksm[mm * KSTR + o] = K[((size_t)b * C8_ + o) * N_ + m0 + mm];
        }
        // stage V tile [256 c][64 m] bf16, XOR-swizzled 16B blocks
#pragma unroll
        for (int it = 0; it < 4; ++it) {
            int flat = it * 512 + t;           // 0..2047
            int c = flat >> 3, mo = flat & 7;
            s16x8 v8 = *(const s16x8*)(V + ((size_t)b * C_ + c) * N_ + m0 + mo * 8);
            int byo = (c * 128 + mo * 16) ^ ((c & 7) << 4);
            *(s16x8*)(smem + VS_OFF + byo) = v8;
        }
        __syncthreads();

        // ---- S phase: s_[i] = q[n_s] . k[mg+16i]  (exact f32) ----
        float s_[4];
#pragma unroll
        for (int i = 0; i < 4; ++i) {
            const float* kr = &ksm[(mg + 16 * i) * KSTR];
            float a = 0.f;
#pragma unroll
            for (int c4 = 0; c4 < 8; ++c4) {
                float4 k4 = *(const float4*)&kr[c4 * 4];
                a = fmaf(k4.x, qreg[c4].x, a);
                a = fmaf(k4.y, qreg[c4].y, a);
                a = fmaf(k4.z, qreg[c4].z, a);
                a = fmaf(k4.w, qreg[c4].w, a);
            }
            s_[i] = a;
        }
        // online softmax, row = 16-lane shuffle group
        float tm = fmaxf(fmaxf(s_[0], s_[1]), fmaxf(s_[2], s_[3]));
#pragma unroll
        for (int d = 1; d < 16; d <<= 1) tm = fmaxf(tm, __shfl_xor(tm, d));
        float mn = fmaxf(m_run, tm);
        float f  = __expf(m_run - mn);
        m_run = mn;
        float psum = 0.f;
#pragma unroll
        for (int i = 0; i < 4; ++i) {
            int m = mg + 16 * i;
            short pb = f2bf(__expf(s_[i] - mn));
            psum += bf2f(pb);                       // denominator matches bf16 P
            int byo = (n_s * 128 + m * 2) ^ ((n_s & 7) << 4);
            *(short*)(smem + PS_OFF + byo) = pb;
        }
#pragma unroll
        for (int d = 1; d < 16; d <<= 1) psum += __shfl_xor(psum, d);
        l_run = l_run * f + psum;
        if (mg == 0) fsc[n_s] = f;
        __syncthreads();   // Ps + fsc visible

        // ---- PV phase: MFMA bf16 ----
        float4 f4 = *(const float4*)&fsc[wn * 16 + tq * 4];
        f32x4 fr = {f4.x, f4.y, f4.z, f4.w};
#pragma unroll
        for (int cf = 0; cf < 4; ++cf) acc[cf] *= fr;
#pragma unroll
        for (int kk = 0; kk < 2; ++kk) {
            const int rowA = wn * 16 + tc;
            const int abyo = PS_OFF + ((rowA * 128 + kk * 64 + tq * 16) ^ ((rowA & 7) << 4));
            s16x8 a8 = *(const s16x8*)(smem + abyo);
#pragma unroll
            for (int cf = 0; cf < 4; ++cf) {
                const int rowB = wc * 64 + cf * 16 + tc;
                const int bbyo = VS_OFF + ((rowB * 128 + kk * 64 + tq * 16) ^ ((rowB & 7) << 4));
                s16x8 b8 = *(const s16x8*)(smem + bbyo);
                acc[cf] = __builtin_amdgcn_mfma_f32_16x16x32_bf16(a8, b8, acc[cf], 0, 0, 0);
            }
        }
    }

    if (mg == 0) lrow[n_s] = l_run;
    __syncthreads();

    // epilogue: direct float4 stores in D-layout (4 consecutive n per lane)
    float4 l4 = *(const float4*)&lrow[wn * 16 + tq * 4];
    f32x4 linv = {1.f / l4.x, 1.f / l4.y, 1.f / l4.z, 1.f / l4.w};
#pragma unroll
    for (int cf = 0; cf < 4; ++cf) {
        int c = wc * 64 + cf * 16 + tc;
        size_t g = ((size_t)b * C_ + c) * N_ + n0 + wn * 16 + tq * 4;
        float4 tp = *(const float4*)&TOP[g];
        f32x4 o4 = acc[cf] * linv;
        float4 st = { tp.x + o4.x, tp.y + o4.y, tp.z + o4.z, tp.w + o4.w };
        *(float4*)&OUT[g] = st;
    }
}

// ---------------------------------------------------------------------------
extern "C" void kernel_launch(void* const* d_in, const int* in_sizes, int n_in,
                              void* d_out, int out_size, void* d_ws, size_t ws_size,
                              hipStream_t stream)
{
    const float* top  = (const float*)d_in[0];
    const float* side = (const float*)d_in[1];
    const float* Wq   = (const float*)d_in[2];
    const float* bq   = (const float*)d_in[3];
    const float* Wk   = (const float*)d_in[4];
    const float* bk   = (const float*)d_in[5];
    const float* Wv   = (const float*)d_in[6];
    const float* bv   = (const float*)d_in[7];
    float* out = (float*)d_out;

    float* Qw = (float*)d_ws;                          // [B][32][N] f32, 2 MB
    float* Kw = Qw + (size_t)B_ * C8_ * N_;            // [B][32][N] f32, 2 MB
    short* Vw = (short*)(Kw + (size_t)B_ * C8_ * N_);  // [B][256][N] bf16, 8 MB

    proj_kernel<false><<<dim3(N_ / 128, 1, B_), dim3(256), 0, stream>>>(top,  Wq, bq, Qw, C8_);
    proj_kernel<false><<<dim3(N_ / 128, 1, B_), dim3(256), 0, stream>>>(side, Wk, bk, Kw, C8_);
    proj_kernel<true ><<<dim3(N_ / 128, 8, B_), dim3(256), 0, stream>>>(side, Wv, bv, Vw, C_);
    attn_kernel<<<dim3(N_ / RT, B_), dim3(512), 0, stream>>>(Qw, Kw, Vw, top, out);
}